// Round 21
// baseline (104.139 us; speedup 1.0000x reference)
//
#include <hip/hip_runtime.h>
#include <stdint.h>

// Problem constants (GPT-2 attention block)
#define S_LEN  2048
#define EMBD   1024
#define NHEAD  16
#define HDIM   64
#define BATCHN 2
#define ROWS   (BATCHN * S_LEN)   // 4096 = flattened B*S

using bf16x8 = __attribute__((ext_vector_type(8))) __bf16;
using f32x4  = __attribute__((ext_vector_type(4))) float;
using f32x16 = __attribute__((ext_vector_type(16))) float;
using u32x4  = __attribute__((ext_vector_type(4))) unsigned;

typedef const __attribute__((address_space(1))) void* gas_ptr;
typedef __attribute__((address_space(3)))       void* las_ptr;

// Async global->LDS, 16B per lane. LDS dest = wave-uniform base + lane*16.
__device__ __forceinline__ void load_lds16(const void* g, void* l) {
    __builtin_amdgcn_global_load_lds((gas_ptr)(uintptr_t)g, (las_ptr)(uintptr_t)l, 16, 0, 0);
}

// fp32 -> bf16 round-to-nearest-even
__device__ __forceinline__ unsigned short f2bf(float f) {
    unsigned u = __builtin_bit_cast(unsigned, f);
    u += 0x7fffu + ((u >> 16) & 1u);
    return (unsigned short)(u >> 16);
}

// pack 2 floats -> 1 dword of 2 bf16 (lo = a, hi = b); hw cvt_pk (no builtin)
__device__ __forceinline__ unsigned pkbf(float a, float b) {
    unsigned r;
    asm("v_cvt_pk_bf16_f32 %0, %1, %2" : "=v"(r) : "v"(a), "v"(b));
    return r;
}

// XOR-swizzled element offset within a [R][64] bf16 tile (128B rows, 8 chunks:
// chunk ^= row&7). Fixes 16-way ds_read_b128 conflicts on 128B-stride rows.
__device__ __forceinline__ int swz(int row, int ebase) {
    int byte = (row << 7) + (ebase << 1);
    byte ^= (row & 7) << 4;
    return byte >> 1;
}

// Same for [R][128] bf16 tiles (256B rows, 16 chunks: chunk ^= row&15).
__device__ __forceinline__ int swzV(int row, int ebase) {
    int byte = (row << 8) + (ebase << 1);
    byte ^= (row & 15) << 4;
    return byte >> 1;
}

// Merged fp32->bf16 convert for 3 sources; destinations are contiguous in ws.
__global__ void cvt3_f32_bf16(const float* __restrict__ s0,
                              const float* __restrict__ s1,
                              const float* __restrict__ s2,
                              unsigned short* __restrict__ d,
                              int n0, int n01, int ntot) {
    int i = blockIdx.x * blockDim.x + threadIdx.x;
    int stride = gridDim.x * blockDim.x;
    for (int idx = i * 4; idx < ntot; idx += stride * 4) {
        const float* s; int off;
        if (idx < n0)       { s = s0; off = idx; }
        else if (idx < n01) { s = s1; off = idx - n0; }
        else                { s = s2; off = idx - n01; }
        float4 f = *(const float4*)(s + off);
        uint2 p;
        p.x = (unsigned)f2bf(f.x) | ((unsigned)f2bf(f.y) << 16);
        p.y = (unsigned)f2bf(f.z) | ((unsigned)f2bf(f.w) << 16);
        *(uint2*)(d + idx) = p;
    }
}

#define SCALE_Q 0.18033688011112042f   // 0.125 * log2(e): softmax in exp2 domain

// ---------------------------------------------------------------------------
// QKV projection GEMM — 256x192 tile, 8 waves, 4-phase interleave, grid
// (16,16) = 256 blocks = 1/CU. R21: TRUE COUNTED vmcnt (T4) — the R17-R20
// version drained vmcnt(0) at every K-tile top (waits for loads issued only
// ~3 phases prior; m218: counted-vs-drain = +38-73%). Now A is staged in 4
// QUARTER stages (rows q*32..+31 of BOTH 128-halves = exactly what phase
// q's MFMAs read; 1 load/thread), schedule B@ph0, Aq0+Aq1@ph1, Aq2@ph2,
// Aq3@ph3. Every phase waits vmcnt(6/7), retiring only loads issued 4
// phases (one full K-tile) earlier -> near-zero stall, no drain in loop.
// ds_reads moved AFTER the per-phase vmcnt+barrier (validity point).
// Clamped last-tile stage keeps counts static (attn-proven pattern).
// Epilogue: scatter q(pre-scaled)/k [B,H,S,D], V^T [B,H,D,S].
// ---------------------------------------------------------------------------
__global__ __launch_bounds__(512, 2) void gemm_qkv(
    const unsigned short* __restrict__ A, const unsigned short* __restrict__ B,
    const float* __restrict__ bias,
    unsigned short* __restrict__ qb, unsigned short* __restrict__ kb,
    unsigned short* __restrict__ vb)
{
    __shared__ __align__(16) unsigned short sA[2][256 * 64];
    __shared__ __align__(16) unsigned short sB[2][192 * 64];

    const int tid  = threadIdx.x;
    const int wid  = tid >> 6;        // 0..7
    const int lane = tid & 63;
    const int g    = lane >> 4;       // 0..3
    const int c    = lane & 15;       // 0..15
    const int bm   = blockIdx.x * 256;
    const int bn   = blockIdx.y * 192;
    const int wm2  = (wid >> 2) * 128; // 0,128
    const int wn2  = (wid & 3) * 48;   // 0,48,96,144
    const int K    = EMBD;             // 1024
    const int NKT  = K / 64;           // 16 K-tiles

    f32x4 acc[8][3] = {};

    // B tile: 1536 chunks, 3 loads/thread. Pre-swizzled source (rule #21).
    auto stage_b = [&](int kt, int buf) {
        const int k0 = kt * 64;
#pragma unroll
        for (int i = 0; i < 3; ++i) {
            int cbase = i * 512 + wid * 64;
            int cidx  = cbase + lane;
            int row   = cidx >> 3;            // 0..191
            int col   = ((cidx & 7) ^ (row & 7)) << 3;
            load_lds16(B + (size_t)(bn + row) * K + k0 + col, &sB[buf][cbase * 8]);
        }
    };
    // A quarter qq: rows [qq*32, qq*32+32) of BOTH 128-halves (512 chunks,
    // 1 load/thread). Waves 0-3 -> half0 rows, waves 4-7 -> half1 rows.
    auto stage_aq = [&](int kt, int buf, int qq) {
        const int k0   = kt * 64;
        const int base = (wid < 4) ? (qq * 256 + wid * 64)
                                   : (1024 + qq * 256 + (wid - 4) * 64);
        int cidx = base + lane;
        int row  = cidx >> 3;                 // in quarter-qq row windows
        int col  = ((cidx & 7) ^ (row & 7)) << 3;
        load_lds16(A + (size_t)(bm + row) * K + k0 + col, &sA[buf][base * 8]);
    };

    // prologue: stage tile 0 (order B, q0, q1, q2, q3 — matches loop issue)
    stage_b(0, 0);
#pragma unroll
    for (int qq = 0; qq < 4; ++qq) stage_aq(0, 0, qq);

    for (int kt = 0; kt < NKT; ++kt) {
        const int buf = kt & 1;
        const int nx  = (kt + 1 < NKT) ? kt + 1 : NKT - 1;  // clamp: static counts

        bf16x8 bfr[3][2];
#pragma unroll
        for (int q = 0; q < 4; ++q) {
            // issue-first staging of tile kt+1 (into buf^1)
            if (q == 0) stage_b(nx, buf ^ 1);                      // 3 loads
            if (q == 1) { stage_aq(nx, buf ^ 1, 0); stage_aq(nx, buf ^ 1, 1); }
            if (q == 2) stage_aq(nx, buf ^ 1, 2);                  // 1 load
            if (q == 3) stage_aq(nx, buf ^ 1, 3);                  // 1 load

            // counted wait: retire only this phase's needed region of tile kt
            // (issued 4 phases ago). Outstanding ledger (oldest->newest):
            //  q0: [B3,q0,q1,q2,q3](kt)+[B3](kt+1)=10, need B+q0 -> leave 6
            //  q1: [q1,q2,q3](kt)+[B3,q0,q1](kt+1)=8, need q1   -> leave 7
            //  q2: [q2,q3](kt)+[B3,q0,q1,q2](kt+1)=8, need q2   -> leave 7
            //  q3: [q3](kt)+[B3,q0..q3](kt+1)=8,      need q3   -> leave 7
            if (q == 0) asm volatile("s_waitcnt vmcnt(6)" ::: "memory");
            else        asm volatile("s_waitcnt vmcnt(7)" ::: "memory");
            __builtin_amdgcn_s_barrier();

            // ds_read AFTER the validity barrier: B subtile once (phase 0),
            // A quarter-q subtile per phase
            if (q == 0) {
#pragma unroll
                for (int j = 0; j < 3; ++j)
#pragma unroll
                    for (int kk = 0; kk < 2; ++kk)
                        bfr[j][kk] = *(const bf16x8*)
                            &sB[buf][swz(wn2 + j * 16 + c, kk * 32 + g * 8)];
            }
            bf16x8 af[2][2];
#pragma unroll
            for (int ii = 0; ii < 2; ++ii)
#pragma unroll
                for (int kk = 0; kk < 2; ++kk)
                    af[ii][kk] = *(const bf16x8*)
                        &sA[buf][swz(wm2 + (q * 2 + ii) * 16 + c, kk * 32 + g * 8)];

            __builtin_amdgcn_s_setprio(1);
#pragma unroll
            for (int ii = 0; ii < 2; ++ii)
#pragma unroll
                for (int j = 0; j < 3; ++j)
#pragma unroll
                    for (int kk = 0; kk < 2; ++kk)
                        acc[q * 2 + ii][j] = __builtin_amdgcn_mfma_f32_16x16x32_bf16(
                            af[ii][kk], bfr[j][kk], acc[q * 2 + ii][j], 0, 0, 0);
            __builtin_amdgcn_s_setprio(0);
            __builtin_amdgcn_s_barrier();
        }
    }

    // drain the clamped tail prefetch before epilogue/endpgm (R5 lesson)
    asm volatile("s_waitcnt vmcnt(0)" ::: "memory");

    // epilogue: D row=(lane>>4)*4+r, col=lane&15 within each 16x16 fragment
#pragma unroll
    for (int i = 0; i < 8; ++i)
#pragma unroll
        for (int j = 0; j < 3; ++j) {
            int n = bn + wn2 + j * 16 + c;
            float bv = bias[n];
            int which = n >> 10, h = (n & 1023) >> 6, d = n & 63;
            if (which < 2) {
                unsigned short* dst = (which == 0) ? qb : kb;
                float sc = (which == 0) ? SCALE_Q : 1.0f;
#pragma unroll
                for (int r = 0; r < 4; ++r) {
                    int m = bm + wm2 + i * 16 + g * 4 + r;
                    int b = m >> 11, s = m & 2047;
                    dst[(((size_t)b * NHEAD + h) * S_LEN + s) * HDIM + d] =
                        f2bf((acc[i][j][r] + bv) * sc);
                }
            } else {
                int m0 = bm + wm2 + i * 16 + g * 4;
                int b = m0 >> 11, s0 = m0 & 2047;
                uint2 p;
                p.x = pkbf(acc[i][j][0] + bv, acc[i][j][1] + bv);
                p.y = pkbf(acc[i][j][2] + bv, acc[i][j][3] + bv);
                *(uint2*)&vb[(((size_t)b * NHEAD + h) * HDIM + d) * S_LEN + s0] = p;
            }
        }
}

// ---------------------------------------------------------------------------
// Output-projection GEMM (fp32 out + bias). 128x128 tile, 4 waves, swizzled
// LDS, 1-phase structure (grid 32x8 = 256 blocks fills the chip).
// ---------------------------------------------------------------------------
__global__ __launch_bounds__(256) void gemm_proj(
    const unsigned short* __restrict__ A, const unsigned short* __restrict__ B,
    const float* __restrict__ bias, float* __restrict__ Cout, int M, int N, int K)
{
    __shared__ __align__(16) unsigned short sA[128 * 64];
    __shared__ __align__(16) unsigned short sB[128 * 64];

    const int tid  = threadIdx.x;
    const int wid  = tid >> 6;
    const int lane = tid & 63;
    const int g    = lane >> 4;
    const int c    = lane & 15;
    const int bm   = blockIdx.x * 128;
    const int bn   = blockIdx.y * 128;
    const int wm   = (wid >> 1) * 64;
    const int wn   = (wid & 1) * 64;

    f32x4 acc[4][4] = {};

    for (int k0 = 0; k0 < K; k0 += 64) {
#pragma unroll
        for (int i = 0; i < 4; ++i) {
            int cidx = i * 256 + tid;
            int row  = cidx >> 3;
            int col  = ((cidx & 7) ^ (row & 7)) << 3;
            load_lds16(A + (size_t)(bm + row) * K + k0 + col,
                       &sA[i * 2048 + wid * 512]);
            load_lds16(B + (size_t)(bn + row) * K + k0 + col,
                       &sB[i * 2048 + wid * 512]);
        }
        __syncthreads();
#pragma unroll
        for (int kk = 0; kk < 2; ++kk) {
            bf16x8 af[4], bfr[4];
#pragma unroll
            for (int i = 0; i < 4; ++i)
                af[i] = *(const bf16x8*)&sA[swz(wm + i * 16 + c, kk * 32 + g * 8)];
#pragma unroll
            for (int j = 0; j < 4; ++j)
                bfr[j] = *(const bf16x8*)&sB[swz(wn + j * 16 + c, kk * 32 + g * 8)];
#pragma unroll
            for (int i = 0; i < 4; ++i)
#pragma unroll
                for (int j = 0; j < 4; ++j)
                    acc[i][j] = __builtin_amdgcn_mfma_f32_16x16x32_bf16(
                        af[i], bfr[j], acc[i][j], 0, 0, 0);
        }
        __syncthreads();
    }

#pragma unroll
    for (int i = 0; i < 4; ++i)
#pragma unroll
        for (int j = 0; j < 4; ++j) {
            int n = bn + wn + j * 16 + c;
            float bv = bias[n];
#pragma unroll
            for (int r = 0; r < 4; ++r) {
                int m = bm + wm + i * 16 + g * 4 + r;
                Cout[(size_t)m * N + n] = acc[i][j][r] + bv;
            }
        }
}

// ---------------------------------------------------------------------------
// Flash-style causal attention — 32x32 MFMA, pair-in-block, KVBLK=128
// (R17/R20-verified best: 41.4 us). Unchanged.
// ---------------------------------------------------------------------------
__global__ __launch_bounds__(512) void attn_kernel(
    const unsigned short* __restrict__ qbuf, const unsigned short* __restrict__ kbuf,
    const unsigned short* __restrict__ vtbuf, unsigned short* __restrict__ obuf)
{
    __shared__ __align__(16) unsigned short sK[3][128 * 64];  // [kv][d], swz
    __shared__ __align__(16) unsigned short sV[3][64 * 128];  // [d][kv], swzV

    const int tid  = threadIdx.x;
    const int wid  = tid >> 6;           // 0..7
    const int wg   = wid & 3;            // wave-in-group
    const int grp  = wid >> 2;           // 0 = heavy super (+K stage), 1 = light (+V stage)
    const int lane = tid & 63;
    const int hi   = lane >> 5;          // 0/1: which half-row of the q pair
    const int q5   = lane & 31;          // q column within wave tile

    const int x  = blockIdx.x;           // [0,256)
    const int j  = x >> 5;               // 0..7
    const int bh = x & 31;               // XCD = bh%8 (L2 locality)
    const int b  = bh >> 4, h = bh & 15;

    const int s  = grp ? j : (15 - j);   // this wave-group's q-super
    const int TT = 16 - j;               // 128-tiles staged (heavy's range)

    const unsigned short* Qh = qbuf  + (size_t)bh * S_LEN * HDIM;
    const unsigned short* Kh = kbuf  + (size_t)bh * S_LEN * HDIM;
    const unsigned short* Vt = vtbuf + (size_t)bh * HDIM * S_LEN;

    const int diag64 = 2 * s + (wg >> 1);   // this wave's diagonal 64-tile
    const int qrow0  = 128 * s + 32 * wg;
    const int qg     = qrow0 + q5;          // this lane-pair's q row

    // stage one 128-wide KV tile: waves 0-3 K (16KB), waves 4-7 V^T (16KB);
    // 4 chunks/lane. Pre-swizzled global source, linear LDS dest (rule #21).
    auto stage = [&](int t, int buf) {
#pragma unroll
        for (int i = 0; i < 4; ++i) {
            int cbase = wg * 256 + i * 64;       // wave-uniform chunk base
            int cidx  = cbase + lane;
            if (grp == 0) {                      // K: 128 rows x 128B (8 chunks)
                int row = cidx >> 3, col = ((cidx & 7) ^ (row & 7)) << 3;
                load_lds16(Kh + (size_t)(t * 128 + row) * HDIM + col,
                           &sK[buf][cbase * 8]);
            } else {                             // V^T: 64 rows x 256B (16 chunks)
                int row = cidx >> 4, col = ((cidx & 15) ^ (row & 15)) << 3;
                load_lds16(Vt + (size_t)row * S_LEN + t * 128 + col,
                           &sV[buf][cbase * 8]);
            }
        }
    };

    // Q B-fragments (pre-scaled by 0.125*log2e): col=q5, k=ks*16+hi*8+e
    bf16x8 aq[4];
#pragma unroll
    for (int ks = 0; ks < 4; ++ks)
        aq[ks] = *(const bf16x8*)&Qh[(size_t)qg * HDIM + ks * 16 + hi * 8];

    f32x16 o2[2] = {};               // O[d=32*t2+(r&3)+4hi+8(r>>2)][q]
    float m_i = -1e30f, l_i = 0.f;   // per-lane partial l (pair-combined at end)

    stage(0, 0);
    stage(1, 1);

    for (int tt = 0; tt < TT; ++tt) {
        const int buf = tt % 3;
        // counted wait: own tile-tt loads landed (4), tile tt+1 still in flight
        asm volatile("s_waitcnt vmcnt(4)" ::: "memory");
        __builtin_amdgcn_s_barrier();
        stage(tt + 2 < TT ? tt + 2 : TT - 1, (tt + 2) % 3);  // clamp: distinct buf

#pragma unroll
        for (int half = 0; half < 2; ++half) {
            const int t64 = 2 * tt + half;
            if (t64 > diag64) break;

            // swapped QK^T: acc[t2] = D[kv = t2*32 + rowfmt(r,hi)][q = q5]
            f32x16 acc[2] = {};
            __builtin_amdgcn_s_setprio(1);
#pragma unroll
            for (int ks = 0; ks < 4; ++ks) {
                bf16x8 k0 = *(const bf16x8*)&sK[buf][swz(half * 64 + q5,      ks * 16 + hi * 8)];
                bf16x8 k1 = *(const bf16x8*)&sK[buf][swz(half * 64 + q5 + 32, ks * 16 + hi * 8)];
                acc[0] = __builtin_amdgcn_mfma_f32_32x32x16_bf16(k0, aq[ks], acc[0], 0, 0, 0);
                acc[1] = __builtin_amdgcn_mfma_f32_32x32x16_bf16(k1, aq[ks], acc[1], 0, 0, 0);
            }
            __builtin_amdgcn_s_setprio(0);

            // causal mask (diagonal 64-tile only)
            if (t64 == diag64) {
#pragma unroll
                for (int t2 = 0; t2 < 2; ++t2) {
                    int base = t64 * 64 + t2 * 32 + 4 * hi;
#pragma unroll
                    for (int r = 0; r < 16; ++r)
                        if (base + (r & 3) + 8 * (r >> 2) > qg) acc[t2][r] = -1e30f;
                }
            }

            // in-lane max over 32 values (tree); cross-lane only in rare branch
            float mx[8];
#pragma unroll
            for (int i = 0; i < 8; ++i)
                mx[i] = fmaxf(fmaxf(acc[i >> 2][(i & 3) * 4 + 0], acc[i >> 2][(i & 3) * 4 + 1]),
                              fmaxf(acc[i >> 2][(i & 3) * 4 + 2], acc[i >> 2][(i & 3) * 4 + 3]));
            float pm = fmaxf(fmaxf(fmaxf(mx[0], mx[1]), fmaxf(mx[2], mx[3])),
                             fmaxf(fmaxf(mx[4], mx[5]), fmaxf(mx[6], mx[7])));

            // defer-rescale (T13): wave-uniform trigger keeps m_i pair-consistent
            if (__any(pm > m_i + 8.0f)) {
                float pmr   = fmaxf(pm, __shfl_xor(pm, 32, 64));
                float m_new = fmaxf(m_i, pmr);
                float fac, dm = m_i - m_new;
                asm("v_exp_f32 %0, %1" : "=v"(fac) : "v"(dm));   // exp2 domain
                l_i *= fac;
                m_i  = m_new;
#pragma unroll
                for (int t2 = 0; t2 < 2; ++t2)
#pragma unroll
                    for (int r = 0; r < 16; ++r) o2[t2][r] *= fac;
            }

            // P = exp2(S - m_i); pack bf16 pairs in-register; per-lane sum
            unsigned pd[2][8];
            float lsum = 0.f;
#pragma unroll
            for (int t2 = 0; t2 < 2; ++t2) {
                float ev[16];
#pragma unroll
                for (int r = 0; r < 16; ++r) {
                    float a = acc[t2][r] - m_i;
                    asm("v_exp_f32 %0, %1" : "=v"(ev[r]) : "v"(a));
                }
                float s4[4];
#pragma unroll
                for (int u = 0; u < 4; ++u) {
                    s4[u] = (ev[4 * u] + ev[4 * u + 1]) + (ev[4 * u + 2] + ev[4 * u + 3]);
                    pd[t2][2 * u]     = pkbf(ev[4 * u],     ev[4 * u + 1]);
                    pd[t2][2 * u + 1] = pkbf(ev[4 * u + 2], ev[4 * u + 3]);
                }
                lsum += (s4[0] + s4[1]) + (s4[2] + s4[3]);
            }
            l_i += lsum;

            // PV: B-frag P[kv=ks*16+hi*8+e][q] via permlane32_swap pair
            // exchange: after swap(p0,p2): p0 = {own p0 | partner p2},
            // p2 = {partner p0 | own p2} -> fw[0..3] = p0,p1,p2,p3 directly.
            __builtin_amdgcn_s_setprio(1);
#pragma unroll
            for (int ks = 0; ks < 4; ++ks) {
                const int t2 = ks >> 1, k1 = ks & 1;
                unsigned p0 = pd[t2][4 * k1 + 0], p1 = pd[t2][4 * k1 + 1];
                unsigned p2 = pd[t2][4 * k1 + 2], p3 = pd[t2][4 * k1 + 3];
                asm("v_permlane32_swap_b32 %0, %1" : "+v"(p0), "+v"(p2));
                asm("v_permlane32_swap_b32 %0, %1" : "+v"(p1), "+v"(p3));
                u32x4 fw;
                fw[0] = p0; fw[1] = p1; fw[2] = p2; fw[3] = p3;
                bf16x8 pf = __builtin_bit_cast(bf16x8, fw);
                bf16x8 v0 = *(const bf16x8*)&sV[buf][swzV(q5,      half * 64 + ks * 16 + hi * 8)];
                bf16x8 v1 = *(const bf16x8*)&sV[buf][swzV(q5 + 32, half * 64 + ks * 16 + hi * 8)];
                o2[0] = __builtin_amdgcn_mfma_f32_32x32x16_bf16(v0, pf, o2[0], 0, 0, 0);
                o2[1] = __builtin_amdgcn_mfma_f32_32x32x16_bf16(v1, pf, o2[1], 0, 0, 0);
            }
            __builtin_amdgcn_s_setprio(0);
        }
        // no trailing drain: next iteration's vmcnt(4)+barrier gates reuse
    }

    // drain in-flight clamped tail prefetches before endpgm (R5 lesson)
    asm volatile("s_waitcnt vmcnt(0)" ::: "memory");

    // epilogue: combine the hi-pair's l partials once; 8x 8B stores per lane
    float l_full = l_i + __shfl_xor(l_i, 32, 64);
    float rl = 1.0f / l_full;
    unsigned short* orow = &obuf[((size_t)(b * S_LEN + qg)) * EMBD + h * HDIM];
#pragma unroll
    for (int t2 = 0; t2 < 2; ++t2)
#pragma unroll
        for (int u = 0; u < 4; ++u) {
            uint2 pw;
            pw.x = pkbf(o2[t2][4 * u] * rl,     o2[t2][4 * u + 1] * rl);
            pw.y = pkbf(o2[t2][4 * u + 2] * rl, o2[t2][4 * u + 3] * rl);
            *(uint2*)&orow[t2 * 32 + 4 * hi + 8 * u] = pw;
        }
}

extern "C" void kernel_launch(void* const* d_in, const int* in_sizes, int n_in,
                              void* d_out, int out_size, void* d_ws, size_t ws_size,
                              hipStream_t stream) {
    const float* hidden = (const float*)d_in[0];  // [2,2048,1024]
    const float* w_attn = (const float*)d_in[1];  // [3072,1024]
    const float* b_attn = (const float*)d_in[2];  // [3072]
    const float* w_proj = (const float*)d_in[3];  // [1024,1024]
    const float* b_proj = (const float*)d_in[4];  // [1024]
    float* out = (float*)d_out;                   // [2,2048,1024] fp32

    unsigned short* Xbf  = (unsigned short*)d_ws;          // 4096*1024
    unsigned short* Wabf = Xbf  + (size_t)ROWS * EMBD;     // 3072*1024
    unsigned short* Wpbf = Wabf + (size_t)3 * EMBD * EMBD; // 1024*1024
    unsigned short* qb   = Wpbf + (size_t)EMBD * EMBD;     // [B,H,S,D] (q pre-scaled)
    unsigned short* kb   = qb + (size_t)BATCHN * NHEAD * S_LEN * HDIM;
    unsigned short* vtb  = kb + (size_t)BATCHN * NHEAD * S_LEN * HDIM; // [B,H,D,S]
    unsigned short* ob   = vtb + (size_t)BATCHN * NHEAD * S_LEN * HDIM; // [B,S,E]

    // fp32 -> bf16 converts (single launch; dsts contiguous in ws)
    const int n0   = ROWS * EMBD;
    const int n01  = n0 + 3 * EMBD * EMBD;
    const int ntot = n01 + EMBD * EMBD;
    cvt3_f32_bf16<<<2048, 256, 0, stream>>>(hidden, w_attn, w_proj, Xbf,
                                            n0, n01, ntot);

    // QKV projection: 256x192 tile, counted-vmcnt 4-phase pipeline
    gemm_qkv<<<dim3(ROWS / 256, 3 * EMBD / 192), 512, 0, stream>>>(
        Xbf, Wabf, b_attn, qb, kb, vtb);

    // causal attention: 256 blocks x 8 waves, pair-in-block, KVBLK=128
    attn_kernel<<<dim3(256), 512, 0, stream>>>(qb, kb, vtb, ob);

    // output projection -> fp32 out
    gemm_proj<<<dim3(ROWS / 128, EMBD / 128), 256, 0, stream>>>(
        ob, Wpbf, b_proj, out, ROWS, EMBD, EMBD);
}

// Round 22
// 102.375 us; speedup vs baseline: 1.0172x; 1.0172x over previous
//
#include <hip/hip_runtime.h>
#include <stdint.h>

// Problem constants (GPT-2 attention block)
#define S_LEN  2048
#define EMBD   1024
#define NHEAD  16
#define HDIM   64
#define BATCHN 2
#define ROWS   (BATCHN * S_LEN)   // 4096 = flattened B*S

using bf16x8 = __attribute__((ext_vector_type(8))) __bf16;
using f32x4  = __attribute__((ext_vector_type(4))) float;
using f32x16 = __attribute__((ext_vector_type(16))) float;
using u32x4  = __attribute__((ext_vector_type(4))) unsigned;

typedef const __attribute__((address_space(1))) void* gas_ptr;
typedef __attribute__((address_space(3)))       void* las_ptr;

// Async global->LDS, 16B per lane. LDS dest = wave-uniform base + lane*16.
__device__ __forceinline__ void load_lds16(const void* g, void* l) {
    __builtin_amdgcn_global_load_lds((gas_ptr)(uintptr_t)g, (las_ptr)(uintptr_t)l, 16, 0, 0);
}

// fp32 -> bf16 round-to-nearest-even
__device__ __forceinline__ unsigned short f2bf(float f) {
    unsigned u = __builtin_bit_cast(unsigned, f);
    u += 0x7fffu + ((u >> 16) & 1u);
    return (unsigned short)(u >> 16);
}

// pack 2 floats -> 1 dword of 2 bf16 (lo = a, hi = b); hw cvt_pk (no builtin)
__device__ __forceinline__ unsigned pkbf(float a, float b) {
    unsigned r;
    asm("v_cvt_pk_bf16_f32 %0, %1, %2" : "=v"(r) : "v"(a), "v"(b));
    return r;
}

// XOR-swizzled element offset within a [R][64] bf16 tile (128B rows, 8 chunks:
// chunk ^= row&7). Fixes 16-way ds_read_b128 conflicts on 128B-stride rows.
__device__ __forceinline__ int swz(int row, int ebase) {
    int byte = (row << 7) + (ebase << 1);
    byte ^= (row & 7) << 4;
    return byte >> 1;
}

// Same for [R][128] bf16 tiles (256B rows, 16 chunks: chunk ^= row&15).
__device__ __forceinline__ int swzV(int row, int ebase) {
    int byte = (row << 8) + (ebase << 1);
    byte ^= (row & 15) << 4;
    return byte >> 1;
}

// Merged fp32->bf16 convert for 3 sources; destinations are contiguous in ws.
__global__ void cvt3_f32_bf16(const float* __restrict__ s0,
                              const float* __restrict__ s1,
                              const float* __restrict__ s2,
                              unsigned short* __restrict__ d,
                              int n0, int n01, int ntot) {
    int i = blockIdx.x * blockDim.x + threadIdx.x;
    int stride = gridDim.x * blockDim.x;
    for (int idx = i * 4; idx < ntot; idx += stride * 4) {
        const float* s; int off;
        if (idx < n0)       { s = s0; off = idx; }
        else if (idx < n01) { s = s1; off = idx - n0; }
        else                { s = s2; off = idx - n01; }
        float4 f = *(const float4*)(s + off);
        uint2 p;
        p.x = (unsigned)f2bf(f.x) | ((unsigned)f2bf(f.y) << 16);
        p.y = (unsigned)f2bf(f.z) | ((unsigned)f2bf(f.w) << 16);
        *(uint2*)(d + idx) = p;
    }
}

#define SCALE_Q 0.18033688011112042f   // 0.125 * log2(e): softmax in exp2 domain

// ---------------------------------------------------------------------------
// QKV projection GEMM — 256x192 tile, 8 waves, 4-phase interleave, grid
// (16,16) = 256 blocks = 1/CU (R17-verified). Staging 7 chunks/thread:
// A (4) issued in phase 0, B (3) in phase 1 — early prefetch keeps ~3
// phases of cover before the tile-top vmcnt(0). (R21's finer counted-vmcnt
// quarter-staging regressed: T4 grafts need the co-designed 8-phase
// structure to pay; this 4-phase + early-issue form is the local optimum.)
// Epilogue: scatter q(pre-scaled)/k [B,H,S,D], V^T [B,H,D,S].
// ---------------------------------------------------------------------------
__global__ __launch_bounds__(512, 2) void gemm_qkv(
    const unsigned short* __restrict__ A, const unsigned short* __restrict__ B,
    const float* __restrict__ bias,
    unsigned short* __restrict__ qb, unsigned short* __restrict__ kb,
    unsigned short* __restrict__ vb)
{
    __shared__ __align__(16) unsigned short sA[2][256 * 64];
    __shared__ __align__(16) unsigned short sB[2][192 * 64];

    const int tid  = threadIdx.x;
    const int wid  = tid >> 6;        // 0..7
    const int lane = tid & 63;
    const int g    = lane >> 4;       // 0..3
    const int c    = lane & 15;       // 0..15
    const int bm   = blockIdx.x * 256;
    const int bn   = blockIdx.y * 192;
    const int wm2  = (wid >> 2) * 128; // 0,128
    const int wn2  = (wid & 3) * 48;   // 0,48,96,144
    const int K    = EMBD;             // 1024
    const int NKT  = K / 64;           // 16 K-tiles

    f32x4 acc[8][3] = {};

    auto stage_a = [&](int kt, int buf) {
        const int k0 = kt * 64;
#pragma unroll
        for (int i = 0; i < 4; ++i) {
            int cbase = i * 512 + wid * 64;
            int cidx  = cbase + lane;
            int row   = cidx >> 3;
            int col   = ((cidx & 7) ^ (row & 7)) << 3;
            load_lds16(A + (size_t)(bm + row) * K + k0 + col, &sA[buf][cbase * 8]);
        }
    };
    auto stage_b = [&](int kt, int buf) {
        const int k0 = kt * 64;
#pragma unroll
        for (int i = 0; i < 3; ++i) {
            int cbase = i * 512 + wid * 64;
            int cidx  = cbase + lane;
            int row   = cidx >> 3;
            int col   = ((cidx & 7) ^ (row & 7)) << 3;
            load_lds16(B + (size_t)(bn + row) * K + k0 + col, &sB[buf][cbase * 8]);
        }
    };

    stage_a(0, 0);
    stage_b(0, 0);

    for (int kt = 0; kt < NKT; ++kt) {
        const int buf = kt & 1;
        asm volatile("s_waitcnt vmcnt(0)" ::: "memory");
        __builtin_amdgcn_s_barrier();

        bf16x8 bfr[3][2];
#pragma unroll
        for (int q = 0; q < 4; ++q) {
            if (kt + 1 < NKT) {
                if (q == 0) stage_a(kt + 1, buf ^ 1);
                if (q == 1) stage_b(kt + 1, buf ^ 1);
            }
            if (q == 0) {
#pragma unroll
                for (int j = 0; j < 3; ++j)
#pragma unroll
                    for (int kk = 0; kk < 2; ++kk)
                        bfr[j][kk] = *(const bf16x8*)
                            &sB[buf][swz(wn2 + j * 16 + c, kk * 32 + g * 8)];
            }
            bf16x8 af[2][2];
#pragma unroll
            for (int ii = 0; ii < 2; ++ii)
#pragma unroll
                for (int kk = 0; kk < 2; ++kk)
                    af[ii][kk] = *(const bf16x8*)
                        &sA[buf][swz(wm2 + (q * 2 + ii) * 16 + c, kk * 32 + g * 8)];

            __builtin_amdgcn_s_barrier();
            __builtin_amdgcn_s_setprio(1);
#pragma unroll
            for (int ii = 0; ii < 2; ++ii)
#pragma unroll
                for (int j = 0; j < 3; ++j)
#pragma unroll
                    for (int kk = 0; kk < 2; ++kk)
                        acc[q * 2 + ii][j] = __builtin_amdgcn_mfma_f32_16x16x32_bf16(
                            af[ii][kk], bfr[j][kk], acc[q * 2 + ii][j], 0, 0, 0);
            __builtin_amdgcn_s_setprio(0);
            __builtin_amdgcn_s_barrier();
        }
    }

    asm volatile("s_waitcnt vmcnt(0)" ::: "memory");

#pragma unroll
    for (int i = 0; i < 8; ++i)
#pragma unroll
        for (int j = 0; j < 3; ++j) {
            int n = bn + wn2 + j * 16 + c;
            float bv = bias[n];
            int which = n >> 10, h = (n & 1023) >> 6, d = n & 63;
            if (which < 2) {
                unsigned short* dst = (which == 0) ? qb : kb;
                float sc = (which == 0) ? SCALE_Q : 1.0f;
#pragma unroll
                for (int r = 0; r < 4; ++r) {
                    int m = bm + wm2 + i * 16 + g * 4 + r;
                    int b = m >> 11, s = m & 2047;
                    dst[(((size_t)b * NHEAD + h) * S_LEN + s) * HDIM + d] =
                        f2bf((acc[i][j][r] + bv) * sc);
                }
            } else {
                int m0 = bm + wm2 + i * 16 + g * 4;
                int b = m0 >> 11, s0 = m0 & 2047;
                uint2 p;
                p.x = pkbf(acc[i][j][0] + bv, acc[i][j][1] + bv);
                p.y = pkbf(acc[i][j][2] + bv, acc[i][j][3] + bv);
                *(uint2*)&vb[(((size_t)b * NHEAD + h) * HDIM + d) * S_LEN + s0] = p;
            }
        }
}

// ---------------------------------------------------------------------------
// Output-projection GEMM (fp32 out + bias). 128x128 tile, 4 waves, swizzled
// LDS, 1-phase structure (grid 32x8 = 256 blocks fills the chip).
// ---------------------------------------------------------------------------
__global__ __launch_bounds__(256) void gemm_proj(
    const unsigned short* __restrict__ A, const unsigned short* __restrict__ B,
    const float* __restrict__ bias, float* __restrict__ Cout, int M, int N, int K)
{
    __shared__ __align__(16) unsigned short sA[128 * 64];
    __shared__ __align__(16) unsigned short sB[128 * 64];

    const int tid  = threadIdx.x;
    const int wid  = tid >> 6;
    const int lane = tid & 63;
    const int g    = lane >> 4;
    const int c    = lane & 15;
    const int bm   = blockIdx.x * 128;
    const int bn   = blockIdx.y * 128;
    const int wm   = (wid >> 1) * 64;
    const int wn   = (wid & 1) * 64;

    f32x4 acc[4][4] = {};

    for (int k0 = 0; k0 < K; k0 += 64) {
#pragma unroll
        for (int i = 0; i < 4; ++i) {
            int cidx = i * 256 + tid;
            int row  = cidx >> 3;
            int col  = ((cidx & 7) ^ (row & 7)) << 3;
            load_lds16(A + (size_t)(bm + row) * K + k0 + col,
                       &sA[i * 2048 + wid * 512]);
            load_lds16(B + (size_t)(bn + row) * K + k0 + col,
                       &sB[i * 2048 + wid * 512]);
        }
        __syncthreads();
#pragma unroll
        for (int kk = 0; kk < 2; ++kk) {
            bf16x8 af[4], bfr[4];
#pragma unroll
            for (int i = 0; i < 4; ++i)
                af[i] = *(const bf16x8*)&sA[swz(wm + i * 16 + c, kk * 32 + g * 8)];
#pragma unroll
            for (int j = 0; j < 4; ++j)
                bfr[j] = *(const bf16x8*)&sB[swz(wn + j * 16 + c, kk * 32 + g * 8)];
#pragma unroll
            for (int i = 0; i < 4; ++i)
#pragma unroll
                for (int j = 0; j < 4; ++j)
                    acc[i][j] = __builtin_amdgcn_mfma_f32_16x16x32_bf16(
                        af[i], bfr[j], acc[i][j], 0, 0, 0);
        }
        __syncthreads();
    }

#pragma unroll
    for (int i = 0; i < 4; ++i)
#pragma unroll
        for (int j = 0; j < 4; ++j) {
            int n = bn + wn + j * 16 + c;
            float bv = bias[n];
#pragma unroll
            for (int r = 0; r < 4; ++r) {
                int m = bm + wm + i * 16 + g * 4 + r;
                Cout[(size_t)m * N + n] = acc[i][j][r] + bv;
            }
        }
}

// ---------------------------------------------------------------------------
// Flash-style causal attention — 32x32 MFMA, pair-in-block, KVBLK=128
// (R17/R20-verified best: 41.4 us). Waves 0-3 compute q-super 15-j, waves
// 4-7 compute q-super j, sharing staged K/V. 3-buffer swizzled LDS, counted
// vmcnt(4), one barrier per 128-kv tile. Swapped QK^T (lane-local softmax),
// in-register P via cvt_pk + permlane32_swap, defer-rescale THR=8 (exp2).
// ---------------------------------------------------------------------------
__global__ __launch_bounds__(512) void attn_kernel(
    const unsigned short* __restrict__ qbuf, const unsigned short* __restrict__ kbuf,
    const unsigned short* __restrict__ vtbuf, unsigned short* __restrict__ obuf)
{
    __shared__ __align__(16) unsigned short sK[3][128 * 64];  // [kv][d], swz
    __shared__ __align__(16) unsigned short sV[3][64 * 128];  // [d][kv], swzV

    const int tid  = threadIdx.x;
    const int wid  = tid >> 6;           // 0..7
    const int wg   = wid & 3;            // wave-in-group
    const int grp  = wid >> 2;           // 0 = heavy super (+K stage), 1 = light (+V stage)
    const int lane = tid & 63;
    const int hi   = lane >> 5;          // 0/1: which half-row of the q pair
    const int q5   = lane & 31;          // q column within wave tile

    const int x  = blockIdx.x;           // [0,256)
    const int j  = x >> 5;               // 0..7
    const int bh = x & 31;               // XCD = bh%8 (L2 locality)
    const int b  = bh >> 4, h = bh & 15;

    const int s  = grp ? j : (15 - j);   // this wave-group's q-super
    const int TT = 16 - j;               // 128-tiles staged (heavy's range)

    const unsigned short* Qh = qbuf  + (size_t)bh * S_LEN * HDIM;
    const unsigned short* Kh = kbuf  + (size_t)bh * S_LEN * HDIM;
    const unsigned short* Vt = vtbuf + (size_t)bh * HDIM * S_LEN;

    const int diag64 = 2 * s + (wg >> 1);   // this wave's diagonal 64-tile
    const int qrow0  = 128 * s + 32 * wg;
    const int qg     = qrow0 + q5;          // this lane-pair's q row

    // stage one 128-wide KV tile: waves 0-3 K (16KB), waves 4-7 V^T (16KB);
    // 4 chunks/lane. Pre-swizzled global source, linear LDS dest (rule #21).
    auto stage = [&](int t, int buf) {
#pragma unroll
        for (int i = 0; i < 4; ++i) {
            int cbase = wg * 256 + i * 64;       // wave-uniform chunk base
            int cidx  = cbase + lane;
            if (grp == 0) {                      // K: 128 rows x 128B (8 chunks)
                int row = cidx >> 3, col = ((cidx & 7) ^ (row & 7)) << 3;
                load_lds16(Kh + (size_t)(t * 128 + row) * HDIM + col,
                           &sK[buf][cbase * 8]);
            } else {                             // V^T: 64 rows x 256B (16 chunks)
                int row = cidx >> 4, col = ((cidx & 15) ^ (row & 15)) << 3;
                load_lds16(Vt + (size_t)row * S_LEN + t * 128 + col,
                           &sV[buf][cbase * 8]);
            }
        }
    };

    // Q B-fragments (pre-scaled by 0.125*log2e): col=q5, k=ks*16+hi*8+e
    bf16x8 aq[4];
#pragma unroll
    for (int ks = 0; ks < 4; ++ks)
        aq[ks] = *(const bf16x8*)&Qh[(size_t)qg * HDIM + ks * 16 + hi * 8];

    f32x16 o2[2] = {};               // O[d=32*t2+(r&3)+4hi+8(r>>2)][q]
    float m_i = -1e30f, l_i = 0.f;   // per-lane partial l (pair-combined at end)

    stage(0, 0);
    stage(1, 1);

    for (int tt = 0; tt < TT; ++tt) {
        const int buf = tt % 3;
        // counted wait: own tile-tt loads landed (4), tile tt+1 still in flight
        asm volatile("s_waitcnt vmcnt(4)" ::: "memory");
        __builtin_amdgcn_s_barrier();
        stage(tt + 2 < TT ? tt + 2 : TT - 1, (tt + 2) % 3);  // clamp: distinct buf

#pragma unroll
        for (int half = 0; half < 2; ++half) {
            const int t64 = 2 * tt + half;
            if (t64 > diag64) break;

            // swapped QK^T: acc[t2] = D[kv = t2*32 + rowfmt(r,hi)][q = q5]
            f32x16 acc[2] = {};
            __builtin_amdgcn_s_setprio(1);
#pragma unroll
            for (int ks = 0; ks < 4; ++ks) {
                bf16x8 k0 = *(const bf16x8*)&sK[buf][swz(half * 64 + q5,      ks * 16 + hi * 8)];
                bf16x8 k1 = *(const bf16x8*)&sK[buf][swz(half * 64 + q5 + 32, ks * 16 + hi * 8)];
                acc[0] = __builtin_amdgcn_mfma_f32_32x32x16_bf16(k0, aq[ks], acc[0], 0, 0, 0);
                acc[1] = __builtin_amdgcn_mfma_f32_32x32x16_bf16(k1, aq[ks], acc[1], 0, 0, 0);
            }
            __builtin_amdgcn_s_setprio(0);

            // causal mask (diagonal 64-tile only)
            if (t64 == diag64) {
#pragma unroll
                for (int t2 = 0; t2 < 2; ++t2) {
                    int base = t64 * 64 + t2 * 32 + 4 * hi;
#pragma unroll
                    for (int r = 0; r < 16; ++r)
                        if (base + (r & 3) + 8 * (r >> 2) > qg) acc[t2][r] = -1e30f;
                }
            }

            // in-lane max over 32 values (tree); cross-lane only in rare branch
            float mx[8];
#pragma unroll
            for (int i = 0; i < 8; ++i)
                mx[i] = fmaxf(fmaxf(acc[i >> 2][(i & 3) * 4 + 0], acc[i >> 2][(i & 3) * 4 + 1]),
                              fmaxf(acc[i >> 2][(i & 3) * 4 + 2], acc[i >> 2][(i & 3) * 4 + 3]));
            float pm = fmaxf(fmaxf(fmaxf(mx[0], mx[1]), fmaxf(mx[2], mx[3])),
                             fmaxf(fmaxf(mx[4], mx[5]), fmaxf(mx[6], mx[7])));

            // defer-rescale (T13): wave-uniform trigger keeps m_i pair-consistent
            if (__any(pm > m_i + 8.0f)) {
                float pmr   = fmaxf(pm, __shfl_xor(pm, 32, 64));
                float m_new = fmaxf(m_i, pmr);
                float fac, dm = m_i - m_new;
                asm("v_exp_f32 %0, %1" : "=v"(fac) : "v"(dm));   // exp2 domain
                l_i *= fac;
                m_i  = m_new;
#pragma unroll
                for (int t2 = 0; t2 < 2; ++t2)
#pragma unroll
                    for (int r = 0; r < 16; ++r) o2[t2][r] *= fac;
            }

            // P = exp2(S - m_i); pack bf16 pairs in-register; per-lane sum
            unsigned pd[2][8];
            float lsum = 0.f;
#pragma unroll
            for (int t2 = 0; t2 < 2; ++t2) {
                float ev[16];
#pragma unroll
                for (int r = 0; r < 16; ++r) {
                    float a = acc[t2][r] - m_i;
                    asm("v_exp_f32 %0, %1" : "=v"(ev[r]) : "v"(a));
                }
                float s4[4];
#pragma unroll
                for (int u = 0; u < 4; ++u) {
                    s4[u] = (ev[4 * u] + ev[4 * u + 1]) + (ev[4 * u + 2] + ev[4 * u + 3]);
                    pd[t2][2 * u]     = pkbf(ev[4 * u],     ev[4 * u + 1]);
                    pd[t2][2 * u + 1] = pkbf(ev[4 * u + 2], ev[4 * u + 3]);
                }
                lsum += (s4[0] + s4[1]) + (s4[2] + s4[3]);
            }
            l_i += lsum;

            // PV: B-frag P[kv=ks*16+hi*8+e][q] via permlane32_swap pair
            // exchange: after swap(p0,p2): p0 = {own p0 | partner p2},
            // p2 = {partner p0 | own p2} -> fw[0..3] = p0,p1,p2,p3 directly.
            __builtin_amdgcn_s_setprio(1);
#pragma unroll
            for (int ks = 0; ks < 4; ++ks) {
                const int t2 = ks >> 1, k1 = ks & 1;
                unsigned p0 = pd[t2][4 * k1 + 0], p1 = pd[t2][4 * k1 + 1];
                unsigned p2 = pd[t2][4 * k1 + 2], p3 = pd[t2][4 * k1 + 3];
                asm("v_permlane32_swap_b32 %0, %1" : "+v"(p0), "+v"(p2));
                asm("v_permlane32_swap_b32 %0, %1" : "+v"(p1), "+v"(p3));
                u32x4 fw;
                fw[0] = p0; fw[1] = p1; fw[2] = p2; fw[3] = p3;
                bf16x8 pf = __builtin_bit_cast(bf16x8, fw);
                bf16x8 v0 = *(const bf16x8*)&sV[buf][swzV(q5,      half * 64 + ks * 16 + hi * 8)];
                bf16x8 v1 = *(const bf16x8*)&sV[buf][swzV(q5 + 32, half * 64 + ks * 16 + hi * 8)];
                o2[0] = __builtin_amdgcn_mfma_f32_32x32x16_bf16(v0, pf, o2[0], 0, 0, 0);
                o2[1] = __builtin_amdgcn_mfma_f32_32x32x16_bf16(v1, pf, o2[1], 0, 0, 0);
            }
            __builtin_amdgcn_s_setprio(0);
        }
        // no trailing drain: next iteration's vmcnt(4)+barrier gates reuse
    }

    // drain in-flight clamped tail prefetches before endpgm (R5 lesson)
    asm volatile("s_waitcnt vmcnt(0)" ::: "memory");

    // epilogue: combine the hi-pair's l partials once; 8x 8B stores per lane
    float l_full = l_i + __shfl_xor(l_i, 32, 64);
    float rl = 1.0f / l_full;
    unsigned short* orow = &obuf[((size_t)(b * S_LEN + qg)) * EMBD + h * HDIM];
#pragma unroll
    for (int t2 = 0; t2 < 2; ++t2)
#pragma unroll
        for (int u = 0; u < 4; ++u) {
            uint2 pw;
            pw.x = pkbf(o2[t2][4 * u] * rl,     o2[t2][4 * u + 1] * rl);
            pw.y = pkbf(o2[t2][4 * u + 2] * rl, o2[t2][4 * u + 3] * rl);
            *(uint2*)&orow[t2 * 32 + 4 * hi + 8 * u] = pw;
        }
}

extern "C" void kernel_launch(void* const* d_in, const int* in_sizes, int n_in,
                              void* d_out, int out_size, void* d_ws, size_t ws_size,
                              hipStream_t stream) {
    const float* hidden = (const float*)d_in[0];  // [2,2048,1024]
    const float* w_attn = (const float*)d_in[1];  // [3072,1024]
    const float* b_attn = (const float*)d_in[2];  // [3072]
    const float* w_proj = (const float*)d_in[3];  // [1024,1024]
    const float* b_proj = (const float*)d_in[4];  // [1024]
    float* out = (float*)d_out;                   // [2,2048,1024] fp32

    unsigned short* Xbf  = (unsigned short*)d_ws;          // 4096*1024
    unsigned short* Wabf = Xbf  + (size_t)ROWS * EMBD;     // 3072*1024
    unsigned short* Wpbf = Wabf + (size_t)3 * EMBD * EMBD; // 1024*1024
    unsigned short* qb   = Wpbf + (size_t)EMBD * EMBD;     // [B,H,S,D] (q pre-scaled)
    unsigned short* kb   = qb + (size_t)BATCHN * NHEAD * S_LEN * HDIM;
    unsigned short* vtb  = kb + (size_t)BATCHN * NHEAD * S_LEN * HDIM; // [B,H,D,S]
    unsigned short* ob   = vtb + (size_t)BATCHN * NHEAD * S_LEN * HDIM; // [B,S,E]

    // fp32 -> bf16 converts (single launch; dsts contiguous in ws)
    const int n0   = ROWS * EMBD;
    const int n01  = n0 + 3 * EMBD * EMBD;
    const int ntot = n01 + EMBD * EMBD;
    cvt3_f32_bf16<<<2048, 256, 0, stream>>>(hidden, w_attn, w_proj, Xbf,
                                            n0, n01, ntot);

    // QKV projection: 256x192 tile -> grid (16,16) = 256 blocks = 1/CU
    gemm_qkv<<<dim3(ROWS / 256, 3 * EMBD / 192), 512, 0, stream>>>(
        Xbf, Wabf, b_attn, qb, kb, vtb);

    // causal attention: 256 blocks x 8 waves, pair-in-block, KVBLK=128
    attn_kernel<<<dim3(256), 512, 0, stream>>>(qb, kb, vtb, ob);

    // output projection -> fp32 out
    gemm_proj<<<dim3(ROWS / 128, EMBD / 128), 256, 0, stream>>>(
        ob, Wpbf, b_proj, out, ROWS, EMBD, EMBD);
}